// Round 1
// 160.977 us; speedup vs baseline: 1.0099x; 1.0099x over previous
//
#include <hip/hip_runtime.h>

#define BB 2
#define CC 64
#define HH 128
#define WW 128
#define HWN (HH*WW)          // 16384
#define CHW (CC*HWN)         // 2^20

// deform tiling
#define BAND_H 8
#define HALO   7             // dilation 5 + bilinear 1 + guard 1; outliers -> global fallback
#define NBAND  (HH / BAND_H) // 16
#define LROWS  (BAND_H + 2 * HALO)     // 22
#define CPB    4
#define XPAD   8
#define XSTR   (WW + 2 * XPAD)         // 144 (zero-padded row)
// interleaved LDS: float4 {c0,c1,c2,c3} per texel; total 22*144*16 B = 49.5 KB -> 3 blocks/CU

// osum tiling
#define OB_H 16
#define OB_HALO 7
#define OB_ROWS (OB_H + 2 * OB_HALO)   // 30
#define OSTR 144                        // 128 + 2*8 zero-pad cols

// Stage 1: osum = BN(bias(dw1x15)) + BN(bias(dw15x1)) + BN(bias(dw3x3))
// Zero-padded LDS band: all 39 taps unconditional (pad reads give 0, matching
// the reference's skip-outside-image semantics).
__global__ __launch_bounds__(256) void osum_kernel(const float* __restrict__ x,
    const float* __restrict__ w1, const float* __restrict__ b1, const float* __restrict__ s1, const float* __restrict__ g1,
    const float* __restrict__ w2, const float* __restrict__ b2, const float* __restrict__ s2, const float* __restrict__ g2,
    const float* __restrict__ w3, const float* __restrict__ b3, const float* __restrict__ s3, const float* __restrict__ g3,
    float* __restrict__ osum)
{
    __shared__ float xs[OB_ROWS * OSTR];   // 17280 B
    int bid  = blockIdx.x;                 // < BB*CC*8
    int band = bid & 7;
    int bc   = bid >> 3;
    int c    = bc & (CC - 1);
    int bs   = band * OB_H;
    int r_lo_v = bs - OB_HALO;             // virtual (may be <0)

    // zero-fill then interior copy
    for (int i = threadIdx.x; i < (OB_ROWS * OSTR) / 4; i += 256)
        ((float4*)xs)[i] = make_float4(0.f, 0.f, 0.f, 0.f);
    __syncthreads();

    int gstart = r_lo_v < 0 ? 0 : r_lo_v;
    int gend   = r_lo_v + OB_ROWS; if (gend > HH) gend = HH;
    int nitems = (gend - gstart) * (WW / 4);
    const float* xp = x + (size_t)bc * HWN;
    for (int i = threadIdx.x; i < nitems; i += 256) {
        int r = i >> 5, col4 = i & 31;
        int g = gstart + r;
        int lr = g - r_lo_v;
        ((float4*)xs)[lr * (OSTR / 4) + 2 + col4] = ((const float4*)(xp + g * WW))[col4];
    }
    __syncthreads();

    float W1[15], W2[15], W3[9];
    #pragma unroll
    for (int k = 0; k < 15; ++k) { W1[k] = w1[c * 15 + k]; W2[k] = w2[c * 15 + k]; }
    #pragma unroll
    for (int k = 0; k < 9; ++k) W3[k] = w3[c * 9 + k];
    float bb1 = b1[c], ss1 = s1[c], gg1 = g1[c];
    float bb2 = b2[c], ss2 = s2[c], gg2 = g2[c];
    float bb3 = b3[c], ss3 = s3[c], gg3 = g3[c];

    #pragma unroll
    for (int i = 0; i < (OB_H * WW) / 256; ++i) {    // 8 px/thread
        int p = bs * WW + i * 256 + threadIdx.x;
        int h = p >> 7;
        int w = p & (WW - 1);
        int lr = h - r_lo_v;                         // in [7, 23)
        int base = lr * OSTR + XPAD + w;

        float a1 = 0.f;
        #pragma unroll
        for (int k = 0; k < 15; ++k) a1 += xs[base + k - 7] * W1[k];
        float a2 = 0.f;
        #pragma unroll
        for (int k = 0; k < 15; ++k) a2 += xs[base + (k - 7) * OSTR] * W2[k];
        float a3 = 0.f;
        #pragma unroll
        for (int kh = 0; kh < 3; ++kh)
            #pragma unroll
            for (int kw = 0; kw < 3; ++kw)
                a3 += xs[base + (kh - 1) * OSTR + (kw - 1)] * W3[kh * 3 + kw];

        osum[(size_t)bc * HWN + p] = (a1 + bb1) * ss1 + gg1
                                   + (a2 + bb2) * ss2 + gg2
                                   + (a3 + bb3) * ss3 + gg3;
    }
}

// Stage 2 (LDS-tiled): off[b,j,hw] PLANAR = BN(bias(1x1conv(osum, bal_w)))
__global__ __launch_bounds__(256) void off_kernel(const float* __restrict__ osum,
    const float* __restrict__ balw, const float* __restrict__ balb,
    const float* __restrict__ s4, const float* __restrict__ g4,
    float* __restrict__ off)
{
    __shared__ float ls[CC * 128];   // 32 KB
    int bid = blockIdx.x;            // < 256
    int b   = bid >> 7;
    int hw0 = (bid & 127) * 128;

    const float* src = osum + (size_t)b * CHW + hw0;
    #pragma unroll
    for (int i = 0; i < 8; ++i) {
        int idx = threadIdx.x + i * 256;       // < 2048 float4
        int row = idx >> 5, col4 = idx & 31;
        ((float4*)ls)[row * 32 + col4] = *(const float4*)(src + (size_t)row * HWN + col4 * 4);
    }
    __syncthreads();

    int hw = (threadIdx.x & 63) + ((threadIdx.x >> 6) & 1) * 64;
    int og = __builtin_amdgcn_readfirstlane((int)(threadIdx.x >> 7));  // 0 or 1

    float acc[9];
    #pragma unroll
    for (int j = 0; j < 9; ++j) acc[j] = 0.f;
    for (int ic = 0; ic < CC; ++ic) {
        float v = ls[ic * 128 + hw];
        #pragma unroll
        for (int j = 0; j < 9; ++j)
            acc[j] += v * balw[(og * 9 + j) * CC + ic];   // uniform -> s_load
    }
    #pragma unroll
    for (int j = 0; j < 9; ++j) {
        int oc = og * 9 + j;
        off[(size_t)b * (18 * HWN) + (size_t)oc * HWN + hw0 + hw] =
            (acc[j] + balb[oc]) * s4[oc] + g4[oc];
    }
}

// zero-padded global gather (exact: reference mask*clamp == zero-pad sampling)
__device__ __forceinline__ float gz(const float* __restrict__ xp, int y, int x) {
    return ((unsigned)y < (unsigned)HH && (unsigned)x < (unsigned)WW) ? xp[y * WW + x] : 0.f;
}

__device__ __forceinline__ float bil_g(const float* __restrict__ xp, int yy, int xx,
                                       float cxa, float cxb, float wy) {
    float v00 = gz(xp, yy, xx),     v01 = gz(xp, yy, xx + 1);
    float v10 = gz(xp, yy + 1, xx), v11 = gz(xp, yy + 1, xx + 1);
    float ra = cxa * v00 + cxb * v01;
    float rb = cxa * v10 + cxb * v11;
    return ra + wy * (rb - ra);
}

// 4-channel bilinear + weighted accumulate from float4-interleaved corners
__device__ __forceinline__ void bl4(const float4 a, const float4 b, const float4 c, const float4 d,
                                    float cxa, float cxb, float wy,
                                    float w0, float w1, float w2, float w3,
                                    float (&acc)[4])
{
    float ra, rb, s;
    ra = cxa * a.x + cxb * b.x; rb = cxa * c.x + cxb * d.x; s = ra + wy * (rb - ra); acc[0] += s * w0;
    ra = cxa * a.y + cxb * b.y; rb = cxa * c.y + cxb * d.y; s = ra + wy * (rb - ra); acc[1] += s * w1;
    ra = cxa * a.z + cxb * b.z; rb = cxa * c.z + cxb * d.z; s = ra + wy * (rb - ra); acc[2] += s * w2;
    ra = cxa * a.w + cxb * b.w; rb = cxa * c.w + cxb * d.w; s = ra + wy * (rb - ra); acc[3] += s * w3;
}

#define DWP(di) ((di) == 0 ? dw2 : (di) == 1 ? dw3 : (di) == 2 ? dw4 : dw5)

// Stage 3: deformable gather. 4 ch/block (float4-interleaved LDS), zero-padded
// tile (no validity ops in fast path), frac shared across dilations.
// Dilation-overlap dedup: center tap 4 fetches (was 16), edge taps 10 (was 16).
// bid = bcp*16 + band: band in low bits => XCD = band%8 (L2 locality).
__global__ __launch_bounds__(256, 3) void deform_kernel(
    const float* __restrict__ x,
    const float* __restrict__ off,
    const float* __restrict__ dw2, const float* __restrict__ dw3,
    const float* __restrict__ dw4, const float* __restrict__ dw5,
    float* __restrict__ pre)
{
    __shared__ float4 xs4[LROWS * XSTR];       // 50688 B, float4 channel-interleaved

    int bid  = blockIdx.x;                     // < 512
    int band = bid & (NBAND - 1);
    int bcp  = bid >> 4;
    int cp   = bcp & (CC / CPB - 1);           // 0..15
    int b    = bcp >> 4;
    int c0   = cp * CPB;
    int bc0  = b * CC + c0;

    int r_lo_v = band * BAND_H - HALO;         // virtual (may be <0 / >HH-LROWS)

    // zero-fill pads + OOB rows
    for (int i = threadIdx.x; i < LROWS * XSTR; i += 256)
        xs4[i] = make_float4(0.f, 0.f, 0.f, 0.f);
    __syncthreads();

    // interior fill, channel-interleaved transpose: 4 planes -> float4 texels
    int gstart = r_lo_v < 0 ? 0 : r_lo_v;
    int gend   = r_lo_v + LROWS; if (gend > HH) gend = HH;
    int nitems = (gend - gstart) * (WW / 4);
    const float* xp0 = x + (size_t)bc0 * HWN;
    const float* xp1 = xp0 + HWN;
    const float* xp2 = xp1 + HWN;
    const float* xp3 = xp2 + HWN;
    for (int i = threadIdx.x; i < nitems; i += 256) {
        int r = i >> 5, col4 = i & 31;
        int g = gstart + r;
        int lr = g - r_lo_v;
        float4 q0 = ((const float4*)(xp0 + g * WW))[col4];
        float4 q1 = ((const float4*)(xp1 + g * WW))[col4];
        float4 q2 = ((const float4*)(xp2 + g * WW))[col4];
        float4 q3 = ((const float4*)(xp3 + g * WW))[col4];
        float4* dst = &xs4[lr * XSTR + XPAD + col4 * 4];
        dst[0] = make_float4(q0.x, q1.x, q2.x, q3.x);
        dst[1] = make_float4(q0.y, q1.y, q2.y, q3.y);
        dst[2] = make_float4(q0.z, q1.z, q2.z, q3.z);
        dst[3] = make_float4(q0.w, q1.w, q2.w, q3.w);
    }
    __syncthreads();

    const float4* XS4 = xs4;
    const float* offb = off + (size_t)b * (18 * HWN);
    const float* xpc[4] = { xp0, xp1, xp2, xp3 };

    // center-tap combined weight (all 4 dilations sample identical corners)
    float wc[4];
    #pragma unroll
    for (int j = 0; j < 4; ++j)
        wc[j] = dw2[(c0 + j) * 9 + 4] + dw3[(c0 + j) * 9 + 4]
              + dw4[(c0 + j) * 9 + 4] + dw5[(c0 + j) * 9 + 4];

    #pragma unroll 1
    for (int chunk = 0; chunk < (BAND_H * WW) / 256; ++chunk) {
        int p = band * (BAND_H * WW) + chunk * 256 + (int)threadIdx.x;
        float hf = (float)(p >> 7);
        float wf = (float)(p & (WW - 1));

        float oy[9], ox[9];
        #pragma unroll
        for (int k = 0; k < 9; ++k) {                   // planar, fully coalesced
            oy[k] = offb[((size_t)(2 * k) << 14) + p];
            ox[k] = offb[((size_t)(2 * k + 1) << 14) + p];
        }

        float acc[4] = {0.f, 0.f, 0.f, 0.f};
        #pragma unroll
        for (int k = 0; k < 9; ++k) {
            const int ky = k / 3 - 1, kx = k % 3 - 1;
            // d*ky is an integer => frac/floor/bilinear weights shared over di
            float pyb = oy[k] + hf;
            float pxb = ox[k] + wf;
            float y0f = floorf(pyb), x0f = floorf(pxb);
            float wy = pyb - y0f, wx = pxb - x0f;
            int y0g = (int)y0f, x0g = (int)x0f;
            int y0b = y0g - r_lo_v;                      // LDS row of base
            int x0b = x0g + XPAD;                        // LDS col
            float cxa = 1.f - wx, cxb = wx;

            // one residency check covers all 4 dilations (extremes compile-time)
            const int dkyLo = (ky < 0) ? -5 : (ky > 0 ? 2 : 0);
            const int dkyHi = (ky < 0) ? -2 : (ky > 0 ? 5 : 0);
            const int dkxLo = (kx < 0) ? -5 : (kx > 0 ? 2 : 0);
            const int dkxHi = (kx < 0) ? -2 : (kx > 0 ? 5 : 0);
            bool ok = (y0b + dkyLo >= 0) & (y0b + dkyHi <= LROWS - 2)
                    & (x0b + dkxLo >= 0) & (x0b + dkxHi <= XSTR - 2);

            if (ok) {
                if (ky == 0 && kx == 0) {
                    // center: single sample, pre-summed weight
                    int f0 = y0b * XSTR + x0b;
                    float4 a = XS4[f0],        bq = XS4[f0 + 1];
                    float4 cq = XS4[f0 + XSTR], dq = XS4[f0 + XSTR + 1];
                    bl4(a, bq, cq, dq, cxa, cxb, wy, wc[0], wc[1], wc[2], wc[3], acc);
                } else if (ky == 0) {
                    // horizontal edge: rows fixed, 6-texel col window shared over di
                    int cbase = x0b + (kx < 0 ? -5 : 2);
                    int f0 = y0b * XSTR + cbase, f1 = f0 + XSTR;
                    float4 top[5], bot[5];
                    #pragma unroll
                    for (int j = 0; j < 5; ++j) { top[j] = XS4[f0 + j]; bot[j] = XS4[f1 + j]; }
                    #pragma unroll
                    for (int di = 0; di < 4; ++di) {
                        const int jj = (kx < 0) ? (3 - di) : di;
                        const float* dwp = DWP(di);
                        bl4(top[jj], top[jj + 1], bot[jj], bot[jj + 1], cxa, cxb, wy,
                            dwp[(c0 + 0) * 9 + k], dwp[(c0 + 1) * 9 + k],
                            dwp[(c0 + 2) * 9 + k], dwp[(c0 + 3) * 9 + k], acc);
                    }
                } else if (kx == 0) {
                    // vertical edge: cols fixed, 6-texel row window shared over di
                    int rbase = y0b + (ky < 0 ? -5 : 2);
                    float4 L[5], R[5];
                    #pragma unroll
                    for (int j = 0; j < 5; ++j) {
                        int f = (rbase + j) * XSTR + x0b;
                        L[j] = XS4[f]; R[j] = XS4[f + 1];
                    }
                    #pragma unroll
                    for (int di = 0; di < 4; ++di) {
                        const int jj = (ky < 0) ? (3 - di) : di;
                        const float* dwp = DWP(di);
                        bl4(L[jj], R[jj], L[jj + 1], R[jj + 1], cxa, cxb, wy,
                            dwp[(c0 + 0) * 9 + k], dwp[(c0 + 1) * 9 + k],
                            dwp[(c0 + 2) * 9 + k], dwp[(c0 + 3) * 9 + k], acc);
                    }
                } else {
                    // diagonal corner taps: no overlap across dilations
                    #pragma unroll
                    for (int di = 0; di < 4; ++di) {
                        const int d = di + 2;
                        int f0 = (y0b + d * ky) * XSTR + (x0b + d * kx);
                        float4 a = XS4[f0],        bq = XS4[f0 + 1];
                        float4 cq = XS4[f0 + XSTR], dq = XS4[f0 + XSTR + 1];
                        const float* dwp = DWP(di);
                        bl4(a, bq, cq, dq, cxa, cxb, wy,
                            dwp[(c0 + 0) * 9 + k], dwp[(c0 + 1) * 9 + k],
                            dwp[(c0 + 2) * 9 + k], dwp[(c0 + 3) * 9 + k], acc);
                    }
                }
            } else {                                     // rare outlier: global zero-pad
                if (ky == 0 && kx == 0) {
                    #pragma unroll
                    for (int j = 0; j < 4; ++j)
                        acc[j] += bil_g(xpc[j], y0g, x0g, cxa, cxb, wy) * wc[j];
                } else {
                    #pragma unroll
                    for (int di = 0; di < 4; ++di) {
                        const int d = di + 2;
                        int yy = y0g + d * ky, xx = x0g + d * kx;
                        const float* dwp = DWP(di);
                        #pragma unroll
                        for (int j = 0; j < 4; ++j)
                            acc[j] += bil_g(xpc[j], yy, xx, cxa, cxb, wy) * dwp[(c0 + j) * 9 + k];
                    }
                }
            }
        }
        #pragma unroll
        for (int j = 0; j < 4; ++j)
            pre[((size_t)(bc0 + j) << 14) + p] = acc[j];
    }
}

// Stage 4 (LDS-tiled): out = (BN(bias(1x1conv(pre, fin_w)))) * x
__global__ __launch_bounds__(256) void final_kernel(const float* __restrict__ pre,
    const float* __restrict__ finw, const float* __restrict__ finb,
    const float* __restrict__ s5, const float* __restrict__ g5,
    const float* __restrict__ x, float* __restrict__ out)
{
    __shared__ float ls[CC * 64];   // 16 KB
    int bid = blockIdx.x;           // < 512
    int b   = bid >> 8;
    int hw0 = (bid & 255) * 64;

    const float* src = pre + (size_t)b * CHW + hw0;
    #pragma unroll
    for (int i = 0; i < 4; ++i) {
        int idx = threadIdx.x + i * 256;      // < 1024 float4
        int row = idx >> 4, col4 = idx & 15;
        ((float4*)ls)[row * 16 + col4] = *(const float4*)(src + (size_t)row * HWN + col4 * 4);
    }
    __syncthreads();

    int hw = threadIdx.x & 63;
    int og = __builtin_amdgcn_readfirstlane((int)(threadIdx.x >> 6));  // 0..3

    float acc[16];
    #pragma unroll
    for (int j = 0; j < 16; ++j) acc[j] = 0.f;
    for (int ic = 0; ic < CC; ++ic) {
        float v = ls[ic * 64 + hw];
        #pragma unroll
        for (int j = 0; j < 16; ++j)
            acc[j] += v * finw[(og * 16 + j) * CC + ic];   // uniform -> s_load
    }
    #pragma unroll
    for (int j = 0; j < 16; ++j) {
        int oc = og * 16 + j;
        size_t oidx = ((size_t)(b * CC + oc) << 14) + hw0 + hw;
        out[oidx] = ((acc[j] + finb[oc]) * s5[oc] + g5[oc]) * x[oidx];
    }
}

extern "C" void kernel_launch(void* const* d_in, const int* in_sizes, int n_in,
                              void* d_out, int out_size, void* d_ws, size_t ws_size,
                              hipStream_t stream) {
    const float* x      = (const float*)d_in[0];
    const float* off1_w = (const float*)d_in[1];
    const float* off1_b = (const float*)d_in[2];
    const float* bn1_s  = (const float*)d_in[3];
    const float* bn1_b  = (const float*)d_in[4];
    const float* off2_w = (const float*)d_in[5];
    const float* off2_b = (const float*)d_in[6];
    const float* bn2_s  = (const float*)d_in[7];
    const float* bn2_b  = (const float*)d_in[8];
    const float* off3_w = (const float*)d_in[9];
    const float* off3_b = (const float*)d_in[10];
    const float* bn3_s  = (const float*)d_in[11];
    const float* bn3_b  = (const float*)d_in[12];
    const float* bal_w  = (const float*)d_in[13];
    const float* bal_b  = (const float*)d_in[14];
    const float* bn4_s  = (const float*)d_in[15];
    const float* bn4_b  = (const float*)d_in[16];
    const float* dw2    = (const float*)d_in[17];
    const float* dw3    = (const float*)d_in[18];
    const float* dw4    = (const float*)d_in[19];
    const float* dw5    = (const float*)d_in[20];
    const float* fin_w  = (const float*)d_in[21];
    const float* fin_b  = (const float*)d_in[22];
    const float* bn5_s  = (const float*)d_in[23];
    const float* bn5_b  = (const float*)d_in[24];

    float* ws   = (float*)d_ws;
    float* osum = ws;                              // 8 MB
    float* off  = ws + (size_t)BB * CHW;           // 2.25 MB (planar)
    float* pre  = off + (size_t)BB * 18 * HWN;     // 8 MB

    float* out = (float*)d_out;

    osum_kernel<<<BB * CC * (HH / OB_H), 256, 0, stream>>>(x,
        off1_w, off1_b, bn1_s, bn1_b,
        off2_w, off2_b, bn2_s, bn2_b,
        off3_w, off3_b, bn3_s, bn3_b, osum);
    off_kernel<<<BB * (HWN / 128), 256, 0, stream>>>(osum, bal_w, bal_b, bn4_s, bn4_b, off);
    deform_kernel<<<BB * (CC / CPB) * NBAND, 256, 0, stream>>>(x, off, dw2, dw3, dw4, dw5, pre);
    final_kernel<<<BB * (HWN / 64), 256, 0, stream>>>(pre, fin_w, fin_b, bn5_s, bn5_b, x, out);
}